// Round 4
// baseline (273.077 us; speedup 1.0000x reference)
//
#include <hip/hip_runtime.h>

// out[b,s,i*64+j] = max(x[b,s,i], kernel[i,j])
// B=8, S=2048, I=64, O=64. Output = 2^26 fp32 = 256 MiB. Pure write-bound.
//
// float4 index v: row = v>>10, rem = v&1023, i = rem>>4, kernel float4 = rem.
// Stride is a multiple of 1024 float4s => rem/i/k-fragment are loop-invariant
// per thread (hoisted). Round-3 post-mortem: with a runtime trip count the
// compiler didn't unroll, so each iteration stalled on a single in-flight
// x-load (~105 us, 2.6 TB/s). Fix: exact-fit launch (2^21 threads x 8 iters,
// no remainder), compile-time trip count, full unroll: 8 independent x-loads
// issued back-to-back (MLP x8), then 8 max+nt-store pairs.

typedef float v4f __attribute__((ext_vector_type(4)));

#define TOTAL4 16777216u   // 2^24 float4s
#define NTHREADS 2097152u  // 8192 blocks x 256
#define ITERS 8            // TOTAL4 / NTHREADS
#define ROWSTEP (NTHREADS >> 10)  // rows advanced per iteration

__global__ __launch_bounds__(256) void fuzzy_max_kernel(
    const float* __restrict__ x,
    const float* __restrict__ km,
    float* __restrict__ out) {
  const unsigned v0 = blockIdx.x * blockDim.x + threadIdx.x;
  const unsigned rem = v0 & 1023u;   // invariant: position within 4096-wide row
  const unsigned i = rem >> 4;       // invariant: input-feature index

  // One 16 B load from the 16 KiB kernel table (L1/L2 resident) per thread.
  const v4f k = reinterpret_cast<const v4f*>(km)[rem];

  const unsigned row0 = v0 >> 10;

  // Phase 1: issue all 8 independent x-loads (8 outstanding per wave).
  float xv[ITERS];
#pragma unroll
  for (int it = 0; it < ITERS; ++it) {
    xv[it] = x[((row0 + (unsigned)it * ROWSTEP) << 6) | i];
  }

  // Phase 2: compute + streaming stores (coalesced 16 B/lane).
  v4f* out4 = reinterpret_cast<v4f*>(out);
#pragma unroll
  for (int it = 0; it < ITERS; ++it) {
    v4f o;
    o.x = fmaxf(xv[it], k.x);
    o.y = fmaxf(xv[it], k.y);
    o.z = fmaxf(xv[it], k.z);
    o.w = fmaxf(xv[it], k.w);
    __builtin_nontemporal_store(o, &out4[v0 + (unsigned)it * NTHREADS]);
  }
}

extern "C" void kernel_launch(void* const* d_in, const int* in_sizes, int n_in,
                              void* d_out, int out_size, void* d_ws, size_t ws_size,
                              hipStream_t stream) {
  const float* x = reinterpret_cast<const float*>(d_in[0]);   // (8,2048,64) fp32
  const float* km = reinterpret_cast<const float*>(d_in[1]);  // (64,64) fp32
  float* out = reinterpret_cast<float*>(d_out);

  // Exact fit: 8192 blocks x 256 threads x 8 float4s = 2^24 float4s = out_size/4.
  fuzzy_max_kernel<<<8192, 256, 0, stream>>>(x, km, out);
}